// Round 10
// baseline (540.346 us; speedup 1.0000x reference)
//
#include <hip/hip_runtime.h>
#include <hip/hip_bf16.h>

#define NN 100000
#define NE 1600000
#define HID 64
#define SCAN_BS 256
#define NBLK ((NN + SCAN_BS - 1) / SCAN_BS)   // 391
#define NSLICE 8
#define SLICEN (NN / NSLICE)                  // 12500
#define FCHUNK ((NE + 255) / 256)             // 6250

typedef float f32x4 __attribute__((ext_vector_type(4)));
typedef short bf16x8 __attribute__((ext_vector_type(8)));

__device__ __forceinline__ float bflo(unsigned u) { return __uint_as_float(u << 16); }
__device__ __forceinline__ float bfhi(unsigned u) { return __uint_as_float(u & 0xffff0000u); }
__device__ __forceinline__ unsigned short f2bf(float f) {
    __hip_bfloat16 h = (__hip_bfloat16)f;
    return *(unsigned short*)&h;
}

__device__ __forceinline__ void acc8(float* a, uint4 u) {
    a[0] += bflo(u.x); a[1] += bfhi(u.x);
    a[2] += bflo(u.y); a[3] += bfhi(u.y);
    a[4] += bflo(u.z); a[5] += bfhi(u.z);
    a[6] += bflo(u.w); a[7] += bfhi(u.w);
}

// ---------- x -> bf16 ----------
__global__ void xcast(const float* __restrict__ in, unsigned short* __restrict__ out, int n4) {
    int i = blockIdx.x * blockDim.x + threadIdx.x;
    if (i >= n4) return;
    float4 v = ((const float4*)in)[i];
    ushort4 o;
    o.x = f2bf(v.x); o.y = f2bf(v.y); o.z = f2bf(v.z); o.w = f2bf(v.w);
    ((ushort4*)out)[i] = o;
}

// ---------- CSR build ----------
__global__ void count_kernel(const int* __restrict__ dst, int* __restrict__ degI, int nE) {
    int e = blockIdx.x * blockDim.x + threadIdx.x;
    if (e < nE) atomicAdd(&degI[dst[e]], 1);
}

__global__ void scan1_kernel(const int* __restrict__ degI, int* __restrict__ rowtmp,
                             int* __restrict__ blockSum) {
    __shared__ int tmp[SCAN_BS];
    int t = threadIdx.x;
    int i = blockIdx.x * SCAN_BS + t;
    int d = (i < NN) ? degI[i] : 0;
    tmp[t] = d;
    __syncthreads();
    for (int off = 1; off < SCAN_BS; off <<= 1) {
        int v = (t >= off) ? tmp[t - off] : 0;
        __syncthreads();
        tmp[t] += v;
        __syncthreads();
    }
    if (i < NN) rowtmp[i] = tmp[t] - d;
    if (t == SCAN_BS - 1) blockSum[blockIdx.x] = tmp[t];
}

__global__ void scan2_kernel(const int* __restrict__ blockSum, int* __restrict__ blockOff, int n) {
    __shared__ int tmp[512];
    int t = threadIdx.x;
    tmp[t] = (t < n) ? blockSum[t] : 0;
    __syncthreads();
    for (int off = 1; off < 512; off <<= 1) {
        int v = (t >= off) ? tmp[t - off] : 0;
        __syncthreads();
        tmp[t] += v;
        __syncthreads();
    }
    if (t < n) blockOff[t] = (t == 0) ? 0 : tmp[t - 1];
}

// also initializes cursor = row_ptr so fill_kernel needs no row_ptr read / no memset
__global__ void scan3_kernel(const int* __restrict__ rowtmp, const int* __restrict__ blockOff,
                             int* __restrict__ row_ptr, int* __restrict__ cursor) {
    int i = blockIdx.x * SCAN_BS + threadIdx.x;
    if (i < NN) {
        int v = rowtmp[i] + blockOff[blockIdx.x];
        row_ptr[i] = v;
        cursor[i] = v;
    }
}

// XCD-sliced fill (proven R9): slice ownership = blockIdx % 8 -> each csr/cursor
// slice is written by exactly one XCD's L2; write traffic ~13 MB instead of ~105 MB.
__global__ void fill_kernel(const int* __restrict__ src, const int* __restrict__ dst,
                            int* __restrict__ cursor, int* __restrict__ csr_src, int nE) {
    int slice = blockIdx.x & (NSLICE - 1);
    int chunk = blockIdx.x >> 3;
    int e = chunk * 256 + threadIdx.x;
    if (e >= nE) return;
    int d = dst[e];
    int lo = slice * SLICEN;
    if (d >= lo && d < lo + SLICEN) {
        int pos = atomicAdd(&cursor[d], 1);
        csr_src[pos] = src[e];
    }
}

// ---------- gather/mean: TWO nodes per wave, interleaved loops ----------
// Each wave owns nodes base, base+1. The combined main loop issues both nodes'
// gathers back-to-back (4 uint4 loads in flight for IN=64, 2 for IN=32) before
// any accumulate -> 2x the memory-level parallelism of one-node-per-wave, with
// zero dummy loads. All loop conditions are wave-uniform (deg is per-node).
// Per-node accumulation order (increasing e per lane) and the shuffle-reduce
// tree are identical to the one-node version -> bit-identical results.
template <int IN>
__launch_bounds__(256)
__global__ void aggregate(const int* __restrict__ row_ptr, const int* __restrict__ degI,
                          const int* __restrict__ csr_src,
                          const unsigned short* __restrict__ hin,
                          float* __restrict__ mout) {
    constexpr int LPE = IN / 8;            // lanes per row (uint4 = 8 bf16)
    constexpr int SPLIT = 64 / LPE;        // edge slots per node per wave
    constexpr int UN = (IN == 64) ? 2 : 1; // loads per node per main iter
    int g = threadIdx.x >> 6;
    int lane = threadIdx.x & 63;
    int base = (blockIdx.x * 4 + g) * 2;   // grid sized so base+1 < NN always
    int lane_p = lane & (LPE - 1);
    int sub = lane / LPE;

    int dg0 = degI[base], dg1 = degI[base + 1];
    const int* cs0 = csr_src + row_ptr[base];
    const int* cs1 = csr_src + row_ptr[base + 1];
    const unsigned short* hp = hin + 8 * lane_p;

    float a0[8], a1[8];
#pragma unroll
    for (int i = 0; i < 8; ++i) { a0[i] = 0.f; a1[i] = 0.f; }

    int e0 = sub, e1 = sub;
    bool act0 = (e0 + SPLIT * (UN - 1)) < dg0;
    bool act1 = (e1 + SPLIT * (UN - 1)) < dg1;
    while (act0 || act1) {
        int s00 = 0, s01 = 0, s10 = 0, s11 = 0;
        if (act0) { s00 = cs0[e0]; if (UN == 2) s01 = cs0[e0 + SPLIT]; }
        if (act1) { s10 = cs1[e1]; if (UN == 2) s11 = cs1[e1 + SPLIT]; }
        uint4 u00, u01, u10, u11;
        if (act0) {
            u00 = *(const uint4*)(hp + (size_t)s00 * IN);
            if (UN == 2) u01 = *(const uint4*)(hp + (size_t)s01 * IN);
        }
        if (act1) {
            u10 = *(const uint4*)(hp + (size_t)s10 * IN);
            if (UN == 2) u11 = *(const uint4*)(hp + (size_t)s11 * IN);
        }
        if (act0) { acc8(a0, u00); if (UN == 2) acc8(a0, u01); e0 += SPLIT * UN; }
        if (act1) { acc8(a1, u10); if (UN == 2) acc8(a1, u11); e1 += SPLIT * UN; }
        act0 = (e0 + SPLIT * (UN - 1)) < dg0;
        act1 = (e1 + SPLIT * (UN - 1)) < dg1;
    }
    // short per-node tails (same order/math as before)
    for (; e0 < dg0; e0 += SPLIT) {
        uint4 u = *(const uint4*)(hp + (size_t)cs0[e0] * IN);
        acc8(a0, u);
    }
    for (; e1 < dg1; e1 += SPLIT) {
        uint4 u = *(const uint4*)(hp + (size_t)cs1[e1] * IN);
        acc8(a1, u);
    }

    // reduce across sub-groups; after the full tree ALL lanes hold the totals
#pragma unroll
    for (int m = LPE; m < 64; m <<= 1) {
#pragma unroll
        for (int i = 0; i < 8; ++i) {
            a0[i] += __shfl_xor(a0[i], m);
            a1[i] += __shfl_xor(a1[i], m);
        }
    }
    if (sub == 0) {
        float r = 1.0f / fmaxf((float)dg0, 1.0f);
        float4 v0, v1;
        v0.x = a0[0] * r; v0.y = a0[1] * r; v0.z = a0[2] * r; v0.w = a0[3] * r;
        v1.x = a0[4] * r; v1.y = a0[5] * r; v1.z = a0[6] * r; v1.w = a0[7] * r;
        float* p = mout + (size_t)base * IN + 8 * lane_p;
        *(float4*)p = v0;
        *(float4*)(p + 4) = v1;
    } else if (sub == 1) {
        float r = 1.0f / fmaxf((float)dg1, 1.0f);
        float4 v0, v1;
        v0.x = a1[0] * r; v0.y = a1[1] * r; v0.z = a1[2] * r; v0.w = a1[3] * r;
        v1.x = a1[4] * r; v1.y = a1[5] * r; v1.z = a1[6] * r; v1.w = a1[7] * r;
        float* p = mout + (size_t)(base + 1) * IN + 8 * lane_p;
        *(float4*)p = v0;
        *(float4*)(p + 4) = v1;
    }
}

// ---------- weight prep: f32 [K][64] -> packed bf16 hi/lo B-fragments ----------
__global__ void wprep(const float* __restrict__ Wl0, const float* __restrict__ Wr0,
                      const float* __restrict__ Wl1, const float* __restrict__ Wr1,
                      const float* __restrict__ Wl2, const float* __restrict__ Wr2,
                      const float* __restrict__ W1, unsigned short* __restrict__ out) {
    int b = blockIdx.x;
    int mid, local;
    if (b < 2) { mid = b; local = 0; }                  // K=32 matrices: 1 block each
    else { mid = 2 + (b - 2) / 2; local = (b - 2) & 1; } // K=64 matrices: 2 blocks each
    const float* Ws[8] = {Wl0, Wr0, Wl1, Wr1, Wl2, Wr2, W1, W1 + 64 * 64};
    const int offs[8] = {0, 4096, 8192, 16384, 24576, 32768, 40960, 49152};
    const float* W = Ws[mid];
    int e = local * 256 + threadIdx.x;   // entry = (ks*4+nt)*64 + lane
    int lane = e & 63;
    int fi = e >> 6;                     // ks*4 + nt
    int ks = fi >> 2, nt = fi & 3;
    int lg = lane >> 4, col = lane & 15;
    unsigned short hi[8], lo[8];
#pragma unroll
    for (int j = 0; j < 8; ++j) {
        float w = W[(ks * 32 + lg * 8 + j) * 64 + nt * 16 + col];
        unsigned short h = f2bf(w);
        hi[j] = h;
        lo[j] = f2bf(w - bflo(h));
    }
    unsigned short* dh = out + offs[mid] + ((size_t)(fi * 2 + 0) * 64 + lane) * 8;
    unsigned short* dl = out + offs[mid] + ((size_t)(fi * 2 + 1) * 64 + lane) * 8;
#pragma unroll
    for (int j = 0; j < 8; ++j) { dh[j] = hi[j]; dl[j] = lo[j]; }
}

// ---------- MFMA GEMM: hout = act( mean@Wl + bl + hroot@Wr ) ----------
template <int KIN, bool RELU>
__launch_bounds__(256)
__global__ void sage_gemm(const float* __restrict__ meanv,
                          const unsigned short* __restrict__ hroot,
                          const unsigned short* __restrict__ wl_pk,
                          const unsigned short* __restrict__ wr_pk,
                          const float* __restrict__ bl,
                          unsigned short* __restrict__ hout) {
    constexpr int NKS = KIN / 32;
    int wid = threadIdx.x >> 6, lane = threadIdx.x & 63;
    int tile = blockIdx.x * 4 + wid;
    if (tile >= NN / 16) return;
    int m0 = tile * 16;
    int ar = lane & 15;     // A row / D col
    int lg = lane >> 4;

    bf16x8 ah[NKS];
#pragma unroll
    for (int ks = 0; ks < NKS; ++ks)
        ah[ks] = *(const bf16x8*)(hroot + (size_t)(m0 + ar) * KIN + ks * 32 + lg * 8);

    bf16x8 amh[NKS], aml[NKS];
#pragma unroll
    for (int ks = 0; ks < NKS; ++ks) {
        const float* p = meanv + (size_t)(m0 + ar) * KIN + ks * 32 + lg * 8;
        float4 v0 = *(const float4*)p;
        float4 v1 = *(const float4*)(p + 4);
        float mv[8] = {v0.x, v0.y, v0.z, v0.w, v1.x, v1.y, v1.z, v1.w};
#pragma unroll
        for (int j = 0; j < 8; ++j) {
            unsigned short h = f2bf(mv[j]);
            amh[ks][j] = (short)h;
            aml[ks][j] = (short)f2bf(mv[j] - bflo(h));
        }
    }

#pragma unroll
    for (int nt = 0; nt < 4; ++nt) {
        f32x4 acc = {0.f, 0.f, 0.f, 0.f};
#pragma unroll
        for (int ks = 0; ks < NKS; ++ks) {
            int fi = ks * 4 + nt;
            bf16x8 wlh = *(const bf16x8*)(wl_pk + ((size_t)(fi * 2 + 0) * 64 + lane) * 8);
            bf16x8 wll = *(const bf16x8*)(wl_pk + ((size_t)(fi * 2 + 1) * 64 + lane) * 8);
            bf16x8 wrh = *(const bf16x8*)(wr_pk + ((size_t)(fi * 2 + 0) * 64 + lane) * 8);
            bf16x8 wrl = *(const bf16x8*)(wr_pk + ((size_t)(fi * 2 + 1) * 64 + lane) * 8);
            acc = __builtin_amdgcn_mfma_f32_16x16x32_bf16(amh[ks], wlh, acc, 0, 0, 0);
            acc = __builtin_amdgcn_mfma_f32_16x16x32_bf16(amh[ks], wll, acc, 0, 0, 0);
            acc = __builtin_amdgcn_mfma_f32_16x16x32_bf16(aml[ks], wlh, acc, 0, 0, 0);
            acc = __builtin_amdgcn_mfma_f32_16x16x32_bf16(ah[ks],  wrh, acc, 0, 0, 0);
            acc = __builtin_amdgcn_mfma_f32_16x16x32_bf16(ah[ks],  wrl, acc, 0, 0, 0);
        }
        float b = bl[nt * 16 + ar];
#pragma unroll
        for (int r = 0; r < 4; ++r) {
            float o = acc[r] + b;
            if (RELU) o = fmaxf(o, 0.f);
            hout[(size_t)(m0 + lg * 4 + r) * 64 + nt * 16 + ar] = f2bf(o);
        }
    }
}

// ---------- a1/a2 = h2 @ W1[0:64], h2 @ W1[64:128] ----------
__launch_bounds__(256)
__global__ void pred_gemm(const unsigned short* __restrict__ h2,
                          const unsigned short* __restrict__ wa_pk,
                          const unsigned short* __restrict__ wb_pk,
                          unsigned short* __restrict__ a1,
                          unsigned short* __restrict__ a2) {
    int wid = threadIdx.x >> 6, lane = threadIdx.x & 63;
    int tile = blockIdx.x * 4 + wid;
    if (tile >= NN / 16) return;
    int m0 = tile * 16;
    int ar = lane & 15;
    int lg = lane >> 4;
    bf16x8 ah[2];
#pragma unroll
    for (int ks = 0; ks < 2; ++ks)
        ah[ks] = *(const bf16x8*)(h2 + (size_t)(m0 + ar) * 64 + ks * 32 + lg * 8);
#pragma unroll
    for (int nt = 0; nt < 4; ++nt) {
        f32x4 p = {0.f, 0.f, 0.f, 0.f};
        f32x4 q = {0.f, 0.f, 0.f, 0.f};
#pragma unroll
        for (int ks = 0; ks < 2; ++ks) {
            int fi = ks * 4 + nt;
            bf16x8 wah = *(const bf16x8*)(wa_pk + ((size_t)(fi * 2 + 0) * 64 + lane) * 8);
            bf16x8 wal = *(const bf16x8*)(wa_pk + ((size_t)(fi * 2 + 1) * 64 + lane) * 8);
            bf16x8 wbh = *(const bf16x8*)(wb_pk + ((size_t)(fi * 2 + 0) * 64 + lane) * 8);
            bf16x8 wbl = *(const bf16x8*)(wb_pk + ((size_t)(fi * 2 + 1) * 64 + lane) * 8);
            p = __builtin_amdgcn_mfma_f32_16x16x32_bf16(ah[ks], wah, p, 0, 0, 0);
            p = __builtin_amdgcn_mfma_f32_16x16x32_bf16(ah[ks], wal, p, 0, 0, 0);
            q = __builtin_amdgcn_mfma_f32_16x16x32_bf16(ah[ks], wbh, q, 0, 0, 0);
            q = __builtin_amdgcn_mfma_f32_16x16x32_bf16(ah[ks], wbl, q, 0, 0, 0);
        }
#pragma unroll
        for (int r = 0; r < 4; ++r) {
            size_t off = (size_t)(m0 + lg * 4 + r) * 64 + nt * 16 + ar;
            a1[off] = f2bf(p[r]);
            a2[off] = f2bf(q[r]);
        }
    }
}

// ---------- edge predictor (R4-proven scalar VALU version: one edge per lane) ----------
__launch_bounds__(256)
__global__ void edge_pred(const int* __restrict__ src, const int* __restrict__ dst,
                          const unsigned short* __restrict__ a1, const unsigned short* __restrict__ a2,
                          const float* __restrict__ ea,
                          const float* __restrict__ W1, const float* __restrict__ b1,
                          const float* __restrict__ W2, const float* __restrict__ b2,
                          const float* __restrict__ W3, const float* __restrict__ b3,
                          float* __restrict__ out, int nE) {
    int e = blockIdx.x * blockDim.x + threadIdx.x;
    if (e >= nE) return;
    int s = src[e];
    int d = dst[e];

    const uint4* pa = (const uint4*)(a1 + (size_t)s * 64);
    const uint4* pb = (const uint4*)(a2 + (size_t)d * 64);
    const float4* eav = (const float4*)(ea + (size_t)e * 8);
    float4 v0 = eav[0];
    float4 v1 = eav[1];

    float z1[64];
    const float* wr = W1 + 128 * 64;
#pragma unroll
    for (int j = 0; j < 64; ++j) {
        float a = fmaf(v0.x, wr[j], b1[j]);
        a = fmaf(v0.y, wr[64 + j], a);
        a = fmaf(v0.z, wr[128 + j], a);
        a = fmaf(v0.w, wr[192 + j], a);
        a = fmaf(v1.x, wr[256 + j], a);
        a = fmaf(v1.y, wr[320 + j], a);
        a = fmaf(v1.z, wr[384 + j], a);
        z1[j] = fmaf(v1.w, wr[448 + j], a);
    }

#pragma unroll
    for (int q = 0; q < 8; ++q) {
        uint4 ua = pa[q];
        uint4 ub = pb[q];
        int j0 = q * 8;
        z1[j0 + 0] += bflo(ua.x) + bflo(ub.x);
        z1[j0 + 1] += bfhi(ua.x) + bfhi(ub.x);
        z1[j0 + 2] += bflo(ua.y) + bflo(ub.y);
        z1[j0 + 3] += bfhi(ua.y) + bfhi(ub.y);
        z1[j0 + 4] += bflo(ua.z) + bflo(ub.z);
        z1[j0 + 5] += bfhi(ua.z) + bfhi(ub.z);
        z1[j0 + 6] += bflo(ua.w) + bflo(ub.w);
        z1[j0 + 7] += bfhi(ua.w) + bfhi(ub.w);
    }

    float z2[32];
#pragma unroll
    for (int j = 0; j < 32; ++j) z2[j] = b2[j];
    for (int k = 0; k < 64; ++k) {
        float v = fmaxf(z1[k], 0.0f);
        const float* w = W2 + (size_t)k * 32;
#pragma unroll
        for (int j = 0; j < 32; ++j) z2[j] = fmaf(v, w[j], z2[j]);
    }

    float o = b3[0];
#pragma unroll
    for (int k = 0; k < 32; ++k) o = fmaf(fmaxf(z2[k], 0.0f), W3[k], o);

    out[e] = 1.0f / (1.0f + __expf(-o));
}

extern "C" void kernel_launch(void* const* d_in, const int* in_sizes, int n_in,
                              void* d_out, int out_size, void* d_ws, size_t ws_size,
                              hipStream_t stream) {
    const float* x   = (const float*)d_in[0];
    const int*   ei  = (const int*)d_in[1];
    const float* ea  = (const float*)d_in[2];
    const float* Wl0 = (const float*)d_in[3];
    const float* bl0 = (const float*)d_in[4];
    const float* Wr0 = (const float*)d_in[5];
    const float* Wl1 = (const float*)d_in[6];
    const float* bl1 = (const float*)d_in[7];
    const float* Wr1 = (const float*)d_in[8];
    const float* Wl2 = (const float*)d_in[9];
    const float* bl2 = (const float*)d_in[10];
    const float* Wr2 = (const float*)d_in[11];
    const float* W1  = (const float*)d_in[12];
    const float* b1  = (const float*)d_in[13];
    const float* W2  = (const float*)d_in[14];
    const float* b2  = (const float*)d_in[15];
    const float* W3  = (const float*)d_in[16];
    const float* b3  = (const float*)d_in[17];

    const int* src = ei;
    const int* dst = ei + NE;

    char* ws = (char*)d_ws;
    size_t off = 0;
    auto alloc = [&](size_t bytes) {
        void* p = ws + off;
        off += (bytes + 255) & ~(size_t)255;
        return p;
    };
    unsigned short* xb = (unsigned short*)alloc((size_t)NN * 32 * 2);
    unsigned short* hA = (unsigned short*)alloc((size_t)NN * HID * 2);  // layer0 out; reused as h2
    unsigned short* hB = (unsigned short*)alloc((size_t)NN * HID * 2);  // layer1 out
    unsigned short* a1 = (unsigned short*)alloc((size_t)NN * HID * 2);
    unsigned short* a2 = (unsigned short*)alloc((size_t)NN * HID * 2);
    unsigned short* wpk = (unsigned short*)alloc((size_t)57344 * 2);
    int* degI    = (int*)alloc(NN * sizeof(int));
    int* row_ptr = (int*)alloc(NN * sizeof(int));
    int* rowtmp  = (int*)alloc(NN * sizeof(int));
    int* cursor  = (int*)alloc(NN * sizeof(int));
    int* blockSum= (int*)alloc(512 * sizeof(int));
    int* blockOff= (int*)alloc(512 * sizeof(int));
    int* csr_src = (int*)alloc((size_t)NE * sizeof(int));
    // meanv aliases [a1|a2] (25.6MB): all mean reads complete before pred_gemm writes a1/a2
    float* meanv = (float*)a1;
    float* out = (float*)d_out;

    const int BS = 256;
    dim3 blkE((NE + BS - 1) / BS);
    int n4 = NN * 32 / 4;
    int gemm_blk = (NN / 16 + 3) / 4;   // 1563
    int agg_blk = NN / 8;               // 12500 (2 nodes per wave, 4 waves per block)

    // ---- x -> bf16 + CSR build + weight prep ----
    hipMemsetAsync(degI, 0, NN * sizeof(int), stream);
    xcast<<<(n4 + BS - 1) / BS, BS, 0, stream>>>(x, xb, n4);
    count_kernel<<<blkE, BS, 0, stream>>>(dst, degI, NE);
    scan1_kernel<<<NBLK, SCAN_BS, 0, stream>>>(degI, rowtmp, blockSum);
    scan2_kernel<<<1, 512, 0, stream>>>(blockSum, blockOff, NBLK);
    scan3_kernel<<<NBLK, SCAN_BS, 0, stream>>>(rowtmp, blockOff, row_ptr, cursor);
    fill_kernel<<<NSLICE * FCHUNK, BS, 0, stream>>>(src, dst, cursor, csr_src, NE);
    wprep<<<14, 256, 0, stream>>>(Wl0, Wr0, Wl1, Wr1, Wl2, Wr2, W1, wpk);

    // ---- layer 0 ----
    aggregate<32><<<agg_blk, 256, 0, stream>>>(row_ptr, degI, csr_src, xb, meanv);
    sage_gemm<32, true><<<gemm_blk, 256, 0, stream>>>(meanv, xb, wpk + 0, wpk + 4096, bl0, hA);
    // ---- layer 1 ----
    aggregate<64><<<agg_blk, 256, 0, stream>>>(row_ptr, degI, csr_src, hA, meanv);
    sage_gemm<64, true><<<gemm_blk, 256, 0, stream>>>(meanv, hA, wpk + 8192, wpk + 16384, bl1, hB);
    // ---- layer 2 (no ReLU) ----
    aggregate<64><<<agg_blk, 256, 0, stream>>>(row_ptr, degI, csr_src, hB, meanv);
    sage_gemm<64, false><<<gemm_blk, 256, 0, stream>>>(meanv, hB, wpk + 24576, wpk + 32768, bl2, hA);
    // ---- a1/a2 = h2 @ W1 halves ----
    pred_gemm<<<gemm_blk, 256, 0, stream>>>(hA, wpk + 40960, wpk + 49152, a1, a2);

    // ---- edge predictor (VALU, one edge per lane) ----
    edge_pred<<<blkE, BS, 0, stream>>>(src, dst, a1, a2, ea, W1, b1, W2, b2, W3, b3, out, NE);
}